// Round 21
// baseline (1112.509 us; speedup 1.0000x reference)
//
#include <hip/hip_runtime.h>

typedef short short8 __attribute__((ext_vector_type(8)));
typedef float f32x16 __attribute__((ext_vector_type(16)));

#define NPTS 4096
#define NB   32
#define S    2        // pinned 32-point strips per wave
#define NT   (NPTS / 32)       // 128 scan iterations (full B per block)
#define SCALE (1.0f / 131072.0f)   // 1/(NB*NPTS)

// ---- bf16 split helpers (round-to-nearest-even) ----
__device__ inline unsigned short bf16_rne(float v) {
    unsigned u = __float_as_uint(v);
    unsigned r = u + 0x7FFFu + ((u >> 16) & 1u);
    return (unsigned short)(r >> 16);
}
__device__ inline float bf16_to_f(unsigned short h) {
    return __uint_as_float(((unsigned)h) << 16);
}
__device__ inline void bf_split(float v, unsigned short& h, unsigned short& l) {
    h = bf16_rne(v);
    l = bf16_rne(v - bf16_to_f(h));
}

// ---- pre-pass: pack records; zero d_out ----
__global__ __launch_bounds__(256) void pack_kernel(
    const float* __restrict__ points, const float* __restrict__ gts,
    unsigned short* __restrict__ pk, float* __restrict__ outp)
{
    const int tid = blockIdx.x * 256 + threadIdx.x;   // 0 .. 262143
    if (tid < 3) outp[tid] = 0.0f;                    // reduce accumulates
    const int c   = tid >> 17;                        // cloud
    const int rem = tid & 131071;                     // b*4096 + j
    const float* src = (c ? gts : points) + (size_t)rem * 3;
    const float x = src[0], y = src[1], z = src[2];
    const float hb = x * x + y * y + z * z;
    unsigned short xh, xl, yh, yl, zh, zl, hh, hl;
    bf_split(x, xh, xl); bf_split(y, yh, yl);
    bf_split(z, zh, zl); bf_split(hb, hh, hl);
    const unsigned short ONE = 0x3F80;
    unsigned short r[16] = { xh, yh, zh, ONE, hh,
                             xl, yl, zl, 0,   hl,
                             xh, yh, zh, ONE, hh, 0 };
    int4* dst = (int4*)(pk + (size_t)tid * 16);
    int4 w0, w1;
    w0.x = r[0] | (r[1] << 16);  w0.y = r[2]  | (r[3]  << 16);
    w0.z = r[4] | (r[5] << 16);  w0.w = r[6]  | (r[7]  << 16);
    w1.x = r[8] | (r[9] << 16);  w1.y = r[10] | (r[11] << 16);
    w1.z = r[12]| (r[13]<< 16);  w1.w = r[14] | (r[15] << 16);
    dst[0] = w0; dst[1] = w1;
}

// ---- main: full-B MFMA scan; deferred-tree software pipeline ----
__global__ __launch_bounds__(256, 4) void chamfer_main(
    const float* __restrict__ points, const float* __restrict__ gts,
    const unsigned short* __restrict__ pk, float* __restrict__ mins)
{
    const int d      = blockIdx.x;        // 0..1023
    const int group  = d & 63;            // (dir,b) — members share XCD (mod 8)
    const int member = d >> 6;            // A-chunk 0..15 (256 points each)
    const int dir = group >> 5;
    const int b   = group & 31;

    const float* Ab = (dir ? gts : points) + (size_t)b * NPTS * 3;
    const int w = threadIdx.x >> 6, l = threadIdx.x & 63;
    const int half = l >> 5, c = l & 31;

    // pinned fragments (mfma B operand) — packing identical to verified R5..R20
    short8 af[S];
    #pragma unroll
    for (int s = 0; s < S; ++s) {
        const int i = member * 256 + w * 64 + s * 32 + c;
        const float ax = Ab[i * 3 + 0], ay = Ab[i * 3 + 1], az = Ab[i * 3 + 2];
        const float ha = ax * ax + ay * ay + az * az;
        unsigned short xh, xl, yh, yl, zh, zl, hh, hl;
        bf_split(-2.f * ax, xh, xl);
        bf_split(-2.f * ay, yh, yl);
        bf_split(-2.f * az, zh, zl);
        bf_split(ha, hh, hl);
        const unsigned short ONE = 0x3F80;
        short8 f;
        if (half == 0) {
            f[0]=(short)xh; f[1]=(short)yh; f[2]=(short)zh; f[3]=(short)hh;
            f[4]=(short)ONE; f[5]=(short)xh; f[6]=(short)yh; f[7]=(short)zh;
        } else {
            f[0]=(short)hh; f[1]=(short)ONE; f[2]=(short)xl; f[3]=(short)yl;
            f[4]=(short)zl; f[5]=(short)hl; f[6]=0; f[7]=0;
        }
        af[s] = f;
    }

    // streamed records: the FULL B cloud for this (dir,b)
    const unsigned short* rec =
        pk + (((size_t)(dir ^ 1) * NB + b) * NPTS + (size_t)c) * 16 + half * 8;

    f32x16 zc;
    #pragma unroll
    for (int q = 0; q < 16; ++q) zc[q] = 0.f;

    float mm[S] = {1e30f, 1e30f};

#define TREE(A, MM)                                                            \
    {                                                                          \
        const float t0 = fminf(fminf((A)[0],  (A)[1]),  (A)[2]);               \
        const float t1 = fminf(fminf((A)[3],  (A)[4]),  (A)[5]);               \
        const float t2 = fminf(fminf((A)[6],  (A)[7]),  (A)[8]);               \
        const float t3 = fminf(fminf((A)[9],  (A)[10]), (A)[11]);              \
        const float t4 = fminf(fminf((A)[12], (A)[13]), (A)[14]);              \
        const float u0 = fminf(fminf(t0, t1), t2);                             \
        const float u1 = fminf(fminf(t3, t4), (A)[15]);                        \
        (MM) = fminf(fminf((MM), u0), u1);                                     \
    }

    // 3-deep record prefetch + 1-stage deferred acc consumption:
    // unit t issues MFMAs for record t, then min-trees record t-1's results
    // (drained ~190 cyc earlier) -> MFMA pipe overlaps tree within a wave.
    short8 c0 = *(const short8*)(rec);
    short8 c1 = *(const short8*)(rec + 512);
    short8 c2 = *(const short8*)(rec + 1024);

    f32x16 pa = __builtin_amdgcn_mfma_f32_32x32x16_bf16(c0, af[0], zc, 0, 0, 0);
    f32x16 pb = __builtin_amdgcn_mfma_f32_32x32x16_bf16(c0, af[1], zc, 0, 0, 0);
    c0 = c1; c1 = c2; c2 = *(const short8*)(rec + 3 * 512);

    #pragma unroll 4
    for (int t = 1; t < NT; ++t) {
        const int tn = (t + 3 < NT) ? (t + 3) : (NT - 1);
        const short8 nx = *(const short8*)(rec + (size_t)tn * 512);

        const f32x16 qa = __builtin_amdgcn_mfma_f32_32x32x16_bf16(c0, af[0], zc, 0, 0, 0);
        const f32x16 qb = __builtin_amdgcn_mfma_f32_32x32x16_bf16(c0, af[1], zc, 0, 0, 0);
        TREE(pa, mm[0])
        TREE(pb, mm[1])
        __builtin_amdgcn_sched_barrier(0);   // cap window (spill guard)
        pa = qa; pb = qb;                    // SSA-renamed under unroll
        c0 = c1; c1 = c2; c2 = nx;
    }
    TREE(pa, mm[0])
    TREE(pb, mm[1])
#undef TREE

    // combine halves, clamp, plain store (single writer per a-point)
    #pragma unroll
    for (int s = 0; s < S; ++s) {
        float v = fminf(mm[s], __shfl_xor(mm[s], 32));
        v = fmaxf(v, 0.f);
        if (half == 0) {
            const int ap = member * 256 + w * 64 + s * 32 + c;
            mins[(size_t)group * NPTS + ap] = v;
        }
    }
}

// ---- pass 2: one block per (dir,b) group; 128 total d_out atomics ----
__global__ __launch_bounds__(256) void reduce_kernel(
    const float* __restrict__ mins, float* __restrict__ outp)
{
    const int group = blockIdx.x;          // 0..63
    const int dir   = group >> 5;
    const float* gm = mins + (size_t)group * NPTS;

    float local = 0.f;
    #pragma unroll
    for (int i = 0; i < NPTS / 256; ++i)
        local += sqrtf(gm[threadIdx.x + i * 256]);

    for (int off = 32; off > 0; off >>= 1)
        local += __shfl_down(local, off);
    __shared__ float wsum[4];
    const int w = threadIdx.x >> 6, l = threadIdx.x & 63;
    if (l == 0) wsum[w] = local;
    __syncthreads();
    if (threadIdx.x == 0) {
        const float s = (wsum[0] + wsum[1] + wsum[2] + wsum[3]) * SCALE;
        atomicAdd(&outp[0], s);          // p2g + g2p
        atomicAdd(&outp[1 + dir], s);    // out[1]=p2g, out[2]=g2p
    }
}

extern "C" void kernel_launch(void* const* d_in, const int* in_sizes, int n_in,
                              void* d_out, int out_size, void* d_ws, size_t ws_size,
                              hipStream_t stream) {
    const float* points = (const float*)d_in[0];   // [32][4096][3]
    const float* gts    = (const float*)d_in[1];   // [32][4096][3]
    float* outp = (float*)d_out;

    unsigned short* packed = (unsigned short*)((char*)d_ws + 64);   // 8 MB
    float* mins = (float*)((char*)d_ws + 64 + 8388608);             // 1 MB

    pack_kernel<<<1024, 256, 0, stream>>>(points, gts, packed, outp);
    chamfer_main<<<1024, 256, 0, stream>>>(points, gts, packed, mins);
    reduce_kernel<<<64, 256, 0, stream>>>(mins, outp);
}

// Round 22
// 47.904 us; speedup vs baseline: 23.2239x; 23.2239x over previous
//
#include <hip/hip_runtime.h>

typedef short short8 __attribute__((ext_vector_type(8)));
typedef float f32x16 __attribute__((ext_vector_type(16)));

#define NPTS 4096
#define NB   32
#define S    2        // pinned 32-point strips per wave
#define CHUNKS 2
#define BPTS (NPTS / CHUNKS)   // 2048 B-points per block
#define NT   (BPTS / 32)       // 64 scan iterations
#define SCALE (1.0f / 131072.0f)   // 1/(NB*NPTS)

// ---- bf16 split helpers (round-to-nearest-even) ----
__device__ inline unsigned short bf16_rne(float v) {
    unsigned u = __float_as_uint(v);
    unsigned r = u + 0x7FFFu + ((u >> 16) & 1u);
    return (unsigned short)(r >> 16);
}
__device__ inline float bf16_to_f(unsigned short h) {
    return __uint_as_float(((unsigned)h) << 16);
}
__device__ inline void bf_split(float v, unsigned short& h, unsigned short& l) {
    h = bf16_rne(v);
    l = bf16_rne(v - bf16_to_f(h));
}

// ---- pre-pass: pack records; init mins; zero d_out ----
__global__ __launch_bounds__(256) void pack_kernel(
    const float* __restrict__ points, const float* __restrict__ gts,
    unsigned short* __restrict__ pk, unsigned* __restrict__ minsInit,
    float* __restrict__ outp)
{
    const int tid = blockIdx.x * 256 + threadIdx.x;   // 0 .. 262143
    if (tid < 3) outp[tid] = 0.0f;                    // reduce accumulates
    const int c   = tid >> 17;                        // cloud
    const int rem = tid & 131071;                     // b*4096 + j
    const float* src = (c ? gts : points) + (size_t)rem * 3;
    const float x = src[0], y = src[1], z = src[2];
    const float hb = x * x + y * y + z * z;
    unsigned short xh, xl, yh, yl, zh, zl, hh, hl;
    bf_split(x, xh, xl); bf_split(y, yh, yl);
    bf_split(z, zh, zl); bf_split(hb, hh, hl);
    const unsigned short ONE = 0x3F80;
    unsigned short r[16] = { xh, yh, zh, ONE, hh,
                             xl, yl, zl, 0,   hl,
                             xh, yh, zh, ONE, hh, 0 };
    int4* dst = (int4*)(pk + (size_t)tid * 16);
    int4 w0, w1;
    w0.x = r[0] | (r[1] << 16);  w0.y = r[2]  | (r[3]  << 16);
    w0.z = r[4] | (r[5] << 16);  w0.w = r[6]  | (r[7]  << 16);
    w1.x = r[8] | (r[9] << 16);  w1.y = r[10] | (r[11] << 16);
    w1.z = r[12]| (r[13]<< 16);  w1.w = r[14] | (r[15] << 16);
    dst[0] = w0; dst[1] = w1;
    minsInit[tid] = 0x7F7FFFFFu;   // FLT_MAX (uint order == float order, >=0)
}

// ---- main: half-B MFMA scan per block; 8 blocks/CU for TLP ----
__global__ __launch_bounds__(256, 4) void chamfer_main(
    const float* __restrict__ points, const float* __restrict__ gts,
    const unsigned short* __restrict__ pk, unsigned* __restrict__ minsU)
{
    const int d      = blockIdx.x;        // 0..2047
    const int group  = d & 63;            // (dir,b) — members share XCD (mod 8)
    const int member = (d >> 6) & 15;     // A-chunk 0..15 (256 points each)
    const int chunk  = d >> 10;           // B-half 0..1
    const int dir = group >> 5;
    const int b   = group & 31;

    const float* Ab = (dir ? gts : points) + (size_t)b * NPTS * 3;
    const int w = threadIdx.x >> 6, l = threadIdx.x & 63;
    const int half = l >> 5, c = l & 31;

    // pinned fragments (mfma B operand) — packing identical to verified R5..R20
    short8 af[S];
    #pragma unroll
    for (int s = 0; s < S; ++s) {
        const int i = member * 256 + w * 64 + s * 32 + c;
        const float ax = Ab[i * 3 + 0], ay = Ab[i * 3 + 1], az = Ab[i * 3 + 2];
        const float ha = ax * ax + ay * ay + az * az;
        unsigned short xh, xl, yh, yl, zh, zl, hh, hl;
        bf_split(-2.f * ax, xh, xl);
        bf_split(-2.f * ay, yh, yl);
        bf_split(-2.f * az, zh, zl);
        bf_split(ha, hh, hl);
        const unsigned short ONE = 0x3F80;
        short8 f;
        if (half == 0) {
            f[0]=(short)xh; f[1]=(short)yh; f[2]=(short)zh; f[3]=(short)hh;
            f[4]=(short)ONE; f[5]=(short)xh; f[6]=(short)yh; f[7]=(short)zh;
        } else {
            f[0]=(short)hh; f[1]=(short)ONE; f[2]=(short)xl; f[3]=(short)yl;
            f[4]=(short)zl; f[5]=(short)hl; f[6]=0; f[7]=0;
        }
        af[s] = f;
    }

    // streamed records: this block's half of the B cloud
    const unsigned short* rec =
        pk + (((size_t)(dir ^ 1) * NB + b) * NPTS + (size_t)chunk * BPTS + c) * 16
           + half * 8;

    f32x16 zc;
    #pragma unroll
    for (int q = 0; q < 16; ++q) zc[q] = 0.f;

    float mm[S] = {1e30f, 1e30f};

#define BODY(REG)                                                              \
    {                                                                          \
        _Pragma("unroll")                                                      \
        for (int s = 0; s < S; ++s) {                                          \
            const f32x16 a =                                                   \
                __builtin_amdgcn_mfma_f32_32x32x16_bf16((REG), af[s], zc, 0, 0, 0); \
            const float t0 = fminf(fminf(a[0],  a[1]),  a[2]);                 \
            const float t1 = fminf(fminf(a[3],  a[4]),  a[5]);                 \
            const float t2 = fminf(fminf(a[6],  a[7]),  a[8]);                 \
            const float t3 = fminf(fminf(a[9],  a[10]), a[11]);                \
            const float t4 = fminf(fminf(a[12], a[13]), a[14]);                \
            const float u0 = fminf(fminf(t0, t1), t2);                         \
            const float u1 = fminf(fminf(t3, t4), a[15]);                      \
            mm[s] = fminf(fminf(mm[s], u0), u1);                               \
        }                                                                      \
    }

    short8 cur = *(const short8*)(rec);

    // 2-iteration scheduling window (R16/R18 spill-verified structure)
    #pragma unroll 1
    for (int t = 0; t + 2 < NT; t += 2) {
        const short8 n0 = *(const short8*)(rec + (size_t)(t + 1) * 512);
        const short8 n1 = *(const short8*)(rec + (size_t)(t + 2) * 512);
        BODY(cur)
        BODY(n0)
        __builtin_amdgcn_sched_barrier(0);   // cap window (spill guard)
        cur = n1;
    }
    {   // peeled tail: iterations NT-2, NT-1
        const short8 n0 = *(const short8*)(rec + (size_t)(NT - 1) * 512);
        BODY(cur)
        BODY(n0)
    }
#undef BODY

    // combine halves, clamp, atomicMin (2 writers per a-point)
    #pragma unroll
    for (int s = 0; s < S; ++s) {
        float v = fminf(mm[s], __shfl_xor(mm[s], 32));
        v = fmaxf(v, 0.f);                      // uint-order == float-order
        if (half == 0) {
            const int ap = member * 256 + w * 64 + s * 32 + c;
            atomicMin(&minsU[(size_t)group * NPTS + ap], __float_as_uint(v));
        }
    }
}

// ---- pass 2: one block per (dir,b) group; 128 total d_out atomics ----
__global__ __launch_bounds__(256) void reduce_kernel(
    const float* __restrict__ mins, float* __restrict__ outp)
{
    const int group = blockIdx.x;          // 0..63
    const int dir   = group >> 5;
    const float* gm = mins + (size_t)group * NPTS;

    float local = 0.f;
    #pragma unroll
    for (int i = 0; i < NPTS / 256; ++i)
        local += sqrtf(gm[threadIdx.x + i * 256]);

    for (int off = 32; off > 0; off >>= 1)
        local += __shfl_down(local, off);
    __shared__ float wsum[4];
    const int w = threadIdx.x >> 6, l = threadIdx.x & 63;
    if (l == 0) wsum[w] = local;
    __syncthreads();
    if (threadIdx.x == 0) {
        const float s = (wsum[0] + wsum[1] + wsum[2] + wsum[3]) * SCALE;
        atomicAdd(&outp[0], s);          // p2g + g2p
        atomicAdd(&outp[1 + dir], s);    // out[1]=p2g, out[2]=g2p
    }
}

extern "C" void kernel_launch(void* const* d_in, const int* in_sizes, int n_in,
                              void* d_out, int out_size, void* d_ws, size_t ws_size,
                              hipStream_t stream) {
    const float* points = (const float*)d_in[0];   // [32][4096][3]
    const float* gts    = (const float*)d_in[1];   // [32][4096][3]
    float* outp = (float*)d_out;

    unsigned short* packed = (unsigned short*)((char*)d_ws + 64);   // 8 MB
    unsigned* mins = (unsigned*)((char*)d_ws + 64 + 8388608);       // 1 MB

    pack_kernel<<<1024, 256, 0, stream>>>(points, gts, packed, mins, outp);
    chamfer_main<<<2048, 256, 0, stream>>>(points, gts, packed, mins);
    reduce_kernel<<<64, 256, 0, stream>>>((const float*)mins, outp);
}